// Round 1
// baseline (8073.438 us; speedup 1.0000x reference)
//
#include <hip/hip_runtime.h>

// Problem constants (from reference): BOX=256, OS=1 -> S=256, NC=10, B=16, N=262144
#define S   256
#define NC  10

// One thread per (batch, point). Loads the point's 2 coords + 10 channel
// values (coalesced: lane i reads index n=i within each class row), then
// deposits 4 bilinear corners x 10 channels with global atomicAdd.
__global__ void __launch_bounds__(256)
scatter_cic_kernel(const float* __restrict__ points,
                   const float* __restrict__ values,
                   float* __restrict__ out, int N) {
    const int n = blockIdx.x * blockDim.x + threadIdx.x;
    const int b = blockIdx.y;
    if (n >= N) return;

    const float* pb = points + (size_t)b * 2 * N;
    // match reference arithmetic exactly: p = (coord + 0.5f) * S
    const float px = (pb[n] + 0.5f) * (float)S;
    const float py = (pb[(size_t)N + n] + 0.5f) * (float)S;
    const float xf = floorf(px), yf = floorf(py);
    const float rx = px - xf,  ry = py - yf;
    const int xi = (int)xf, yi = (int)yf;

    // Load all 10 channel values for this point (each read is coalesced
    // across the wave within a class row).
    const float* vb = values + (size_t)b * NC * N + n;
    float v[NC];
#pragma unroll
    for (int c = 0; c < NC; ++c) v[c] = vb[(size_t)c * N];

    float* ob = out + (size_t)b * NC * S * S;

#pragma unroll
    for (int dx = 0; dx < 2; ++dx) {
        const int x_ = xi + dx;
        if (x_ < 0 || x_ >= S) continue;
        const float wx = dx ? rx : (1.0f - rx);
#pragma unroll
        for (int dy = 0; dy < 2; ++dy) {
            const int y_ = yi + dy;
            if (y_ < 0 || y_ >= S) continue;
            const float w = wx * (dy ? ry : (1.0f - ry));
            const int idx = y_ * S + x_;
#pragma unroll
            for (int c = 0; c < NC; ++c) {
                atomicAdd(ob + (size_t)c * S * S + idx, w * v[c]);
            }
        }
    }
}

extern "C" void kernel_launch(void* const* d_in, const int* in_sizes, int n_in,
                              void* d_out, int out_size, void* d_ws, size_t ws_size,
                              hipStream_t stream) {
    const float* points = (const float*)d_in[0];   // [B, 2, N]
    const float* values = (const float*)d_in[1];   // [B, NC, N]
    float* out = (float*)d_out;                    // [B, NC, S, S]

    // Derive B and N from sizes (S, NC fixed by the reference).
    const int B = out_size / (NC * S * S);         // 16
    const int N = in_sizes[0] / (2 * B);           // 262144

    // Output is poisoned with 0xAA before every timed launch -> zero it.
    hipMemsetAsync(d_out, 0, (size_t)out_size * sizeof(float), stream);

    dim3 block(256, 1, 1);
    dim3 grid((N + 255) / 256, B, 1);
    scatter_cic_kernel<<<grid, block, 0, stream>>>(points, values, out, N);
}

// Round 2
// 1219.460 us; speedup vs baseline: 6.6205x; 6.6205x over previous
//
#include <hip/hip_runtime.h>

// Problem constants: BOX=256, OS=1 -> S=256, NC=10, B=16, N=262144
#define S_    256
#define NC_   10
#define CHUNK 4096      // points per binning block (N % CHUNK == 0 required)

typedef unsigned int u32;

__device__ __forceinline__ u32 f2bf(float f) {          // f32 -> bf16 (RNE)
    u32 u = __float_as_uint(f);
    return (u + 0x7fffu + ((u >> 16) & 1u)) >> 16;
}
__device__ __forceinline__ float bf2f(u32 h) { return __uint_as_float(h << 16); }

// ---------------- fast path ----------------
// K1: per-chunk histogram over the 64 (8x8) 32px-tiles of its batch.
// hist[chunk][tile] fully written by its own block -> no pre-zero needed.
__global__ void __launch_bounds__(256)
k_hist(const float* __restrict__ points, u32* __restrict__ hist, int N) {
    __shared__ u32 h[64];
    if (threadIdx.x < 64) h[threadIdx.x] = 0;
    __syncthreads();
    const int cpb = N / CHUNK;
    const int b  = blockIdx.x / cpb;
    const int n0 = (blockIdx.x % cpb) * CHUNK;
    const float* pb = points + (size_t)b * 2 * N;
    for (int i = threadIdx.x; i < CHUNK; i += 256) {
        int n = n0 + i;
        float px = (pb[n] + 0.5f) * (float)S_;
        float py = (pb[(size_t)N + n] + 0.5f) * (float)S_;
        int xi = (int)floorf(px), yi = (int)floorf(py);
        int bin = ((yi >> 5) << 3) + (xi >> 5);          // tiles are 32x32 px
        atomicAdd(&h[bin], 1u);                          // LDS atomic
    }
    __syncthreads();
    if (threadIdx.x < 64) hist[(size_t)blockIdx.x * 64 + threadIdx.x] = h[threadIdx.x];
}

// K2: single block, 1024 threads. Per global bin: total count, exclusive base,
// and per-chunk start cursors (deterministic ranking, no global atomics).
__global__ void __launch_bounds__(1024)
k_scan(const u32* __restrict__ hist, u32* __restrict__ blockStart,
       u32* __restrict__ binBase, u32* __restrict__ binCnt,
       int cpb, int totalBins) {
    __shared__ u32 s[1024];
    const int g = threadIdx.x;
    const int batch = g >> 6, t = g & 63;
    u32 tot = 0;
    if (g < totalBins)
        for (int i = 0; i < cpb; ++i) tot += hist[(size_t)(batch * cpb + i) * 64 + t];
    s[g] = tot;
    __syncthreads();
    for (int off = 1; off < 1024; off <<= 1) {           // inclusive scan
        u32 y = (g >= off) ? s[g - off] : 0;
        __syncthreads();
        s[g] += y;
        __syncthreads();
    }
    if (g < totalBins) {
        u32 base = s[g] - tot;                           // exclusive
        binBase[g] = base;
        binCnt[g]  = tot;
        u32 run = base;
        for (int i = 0; i < cpb; ++i) {
            size_t idx = (size_t)(batch * cpb + i) * 64 + t;
            u32 hv = hist[idx];
            blockStart[idx] = run;
            run += hv;
        }
    }
}

// K3: scatter 32B records into bin-sorted order. Record: px,py (f32) +
// 10 values packed bf16. Slots come from LDS cursors seeded by blockStart.
__global__ void __launch_bounds__(256)
k_scatter(const float* __restrict__ points, const float* __restrict__ values,
          const u32* __restrict__ blockStart, uint4* __restrict__ records, int N) {
    __shared__ u32 cur[64];
    if (threadIdx.x < 64) cur[threadIdx.x] = blockStart[(size_t)blockIdx.x * 64 + threadIdx.x];
    __syncthreads();
    const int cpb = N / CHUNK;
    const int b  = blockIdx.x / cpb;
    const int n0 = (blockIdx.x % cpb) * CHUNK;
    const float* pb = points + (size_t)b * 2 * N;
    const float* vb = values + (size_t)b * NC_ * N;
    for (int i = threadIdx.x; i < CHUNK; i += 256) {
        int n = n0 + i;
        float px = (pb[n] + 0.5f) * (float)S_;
        float py = (pb[(size_t)N + n] + 0.5f) * (float)S_;
        int xi = (int)floorf(px), yi = (int)floorf(py);
        int bin = ((yi >> 5) << 3) + (xi >> 5);
        u32 slot = atomicAdd(&cur[bin], 1u);             // LDS atomic
        float v[NC_];
#pragma unroll
        for (int c = 0; c < NC_; ++c) v[c] = vb[(size_t)c * N + n];
        uint4 r0, r1;
        r0.x = __float_as_uint(px);
        r0.y = __float_as_uint(py);
        r0.z = f2bf(v[0]) | (f2bf(v[1]) << 16);
        r0.w = f2bf(v[2]) | (f2bf(v[3]) << 16);
        r1.x = f2bf(v[4]) | (f2bf(v[5]) << 16);
        r1.y = f2bf(v[6]) | (f2bf(v[7]) << 16);
        r1.z = f2bf(v[8]) | (f2bf(v[9]) << 16);
        r1.w = 0;
        records[(size_t)slot * 2]     = r0;
        records[(size_t)slot * 2 + 1] = r1;
    }
}

// K4: one block per bin. Accumulate into a 33x33x10 LDS tile (f32 ds-atomics),
// then write out: plain stores for the uniquely-owned interior, atomicAdd for
// the shared 1px borders only (~1.3M global atomics total).
__global__ void __launch_bounds__(256)
k_deposit(const uint4* __restrict__ records, const u32* __restrict__ binBase,
          const u32* __restrict__ binCnt, float* __restrict__ out) {
    __shared__ float tile[NC_ * 33 * 33];                // 43,560 B
    for (int i = threadIdx.x; i < NC_ * 1089; i += 256) tile[i] = 0.0f;
    __syncthreads();

    const int g = blockIdx.x;
    const int batch = g >> 6, t = g & 63;
    const int tx = t & 7, ty = t >> 3;
    const int ox = tx * 32, oy = ty * 32;
    const u32 base = binBase[g], cnt = binCnt[g];

    for (u32 i = threadIdx.x; i < cnt; i += 256) {
        uint4 r0 = records[(size_t)(base + i) * 2];
        uint4 r1 = records[(size_t)(base + i) * 2 + 1];
        float px = __uint_as_float(r0.x), py = __uint_as_float(r0.y);
        float xf = floorf(px), yf = floorf(py);
        float rx = px - xf, ry = py - yf;
        int lx = (int)xf - ox, ly = (int)yf - oy;        // in [0,31]
        float w00 = (1.0f - rx) * (1.0f - ry);
        float w10 = rx * (1.0f - ry);
        float w01 = (1.0f - rx) * ry;
        float w11 = rx * ry;
        float v[NC_];
        v[0] = bf2f(r0.z & 0xffffu); v[1] = bf2f(r0.z >> 16);
        v[2] = bf2f(r0.w & 0xffffu); v[3] = bf2f(r0.w >> 16);
        v[4] = bf2f(r1.x & 0xffffu); v[5] = bf2f(r1.x >> 16);
        v[6] = bf2f(r1.y & 0xffffu); v[7] = bf2f(r1.y >> 16);
        v[8] = bf2f(r1.z & 0xffffu); v[9] = bf2f(r1.z >> 16);
        int i00 = ly * 33 + lx;
#pragma unroll
        for (int c = 0; c < NC_; ++c) {
            float* tc = tile + c * 1089 + i00;
            atomicAdd(tc,      w00 * v[c]);
            atomicAdd(tc + 1,  w10 * v[c]);
            atomicAdd(tc + 33, w01 * v[c]);
            atomicAdd(tc + 34, w11 * v[c]);
        }
    }
    __syncthreads();

    float* ob = out + (size_t)batch * NC_ * S_ * S_;
    for (int i = threadIdx.x; i < NC_ * 1089; i += 256) {
        int c = i / 1089, cell = i % 1089;
        int ly = cell / 33, lx = cell % 33;
        int gx = ox + lx, gy = oy + ly;
        if (gx >= S_ || gy >= S_) continue;              // halo off the image
        float val = tile[i];
        float* dst = ob + (size_t)c * S_ * S_ + gy * S_ + gx;
        bool border = (lx == 0) | (lx == 32) | (ly == 0) | (ly == 32);
        if (border) atomicAdd(dst, val);                 // shared with neighbor
        else        *dst = val;                          // unique owner
    }
}

// ---------------- fallback (round-1 correct path) ----------------
__global__ void __launch_bounds__(256)
scatter_cic_kernel(const float* __restrict__ points,
                   const float* __restrict__ values,
                   float* __restrict__ out, int N) {
    const int n = blockIdx.x * blockDim.x + threadIdx.x;
    const int b = blockIdx.y;
    if (n >= N) return;
    const float* pb = points + (size_t)b * 2 * N;
    const float px = (pb[n] + 0.5f) * (float)S_;
    const float py = (pb[(size_t)N + n] + 0.5f) * (float)S_;
    const float xf = floorf(px), yf = floorf(py);
    const float rx = px - xf, ry = py - yf;
    const int xi = (int)xf, yi = (int)yf;
    const float* vb = values + (size_t)b * NC_ * N + n;
    float v[NC_];
#pragma unroll
    for (int c = 0; c < NC_; ++c) v[c] = vb[(size_t)c * N];
    float* ob = out + (size_t)b * NC_ * S_ * S_;
#pragma unroll
    for (int dx = 0; dx < 2; ++dx) {
        const int x_ = xi + dx;
        if (x_ < 0 || x_ >= S_) continue;
        const float wx = dx ? rx : (1.0f - rx);
#pragma unroll
        for (int dy = 0; dy < 2; ++dy) {
            const int y_ = yi + dy;
            if (y_ < 0 || y_ >= S_) continue;
            const float w = wx * (dy ? ry : (1.0f - ry));
            const int idx = y_ * S_ + x_;
#pragma unroll
            for (int c = 0; c < NC_; ++c)
                atomicAdd(ob + (size_t)c * S_ * S_ + idx, w * v[c]);
        }
    }
}

extern "C" void kernel_launch(void* const* d_in, const int* in_sizes, int n_in,
                              void* d_out, int out_size, void* d_ws, size_t ws_size,
                              hipStream_t stream) {
    const float* points = (const float*)d_in[0];   // [B, 2, N]
    const float* values = (const float*)d_in[1];   // [B, NC, N]
    float* out = (float*)d_out;                    // [B, NC, S, S]

    const int B = out_size / (NC_ * S_ * S_);      // 16
    const int N = in_sizes[0] / (2 * B);           // 262144

    hipMemsetAsync(d_out, 0, (size_t)out_size * sizeof(float), stream);

    const size_t P = (size_t)B * N;
    const int cpb = N / CHUNK;                     // chunks per batch (64)
    const int chunksTotal = B * cpb;               // 1024
    const int totalBins = B * 64;                  // 1024

    const size_t recBytes  = P * 32;               // 134.2 MB
    const size_t histElems = (size_t)chunksTotal * 64;
    const size_t wsNeeded  = recBytes + 2 * histElems * 4 + 2 * (size_t)totalBins * 4 + 256;

    const bool fast = (N % CHUNK == 0) && (totalBins <= 1024) && (B == 16) &&
                      (ws_size >= wsNeeded);

    if (fast) {
        char* w = (char*)d_ws;
        uint4* records  = (uint4*)w;
        u32* hist       = (u32*)(w + recBytes);
        u32* blockStart = hist + histElems;
        u32* binBase    = blockStart + histElems;
        u32* binCnt     = binBase + totalBins;

        k_hist<<<chunksTotal, 256, 0, stream>>>(points, hist, N);
        k_scan<<<1, 1024, 0, stream>>>(hist, blockStart, binBase, binCnt, cpb, totalBins);
        k_scatter<<<chunksTotal, 256, 0, stream>>>(points, values, blockStart, records, N);
        k_deposit<<<totalBins, 256, 0, stream>>>(records, binBase, binCnt, out);
    } else {
        dim3 block(256, 1, 1);
        dim3 grid((N + 255) / 256, B, 1);
        scatter_cic_kernel<<<grid, block, 0, stream>>>(points, values, out, N);
    }
}

// Round 3
// 546.823 us; speedup vs baseline: 14.7643x; 2.2301x over previous
//
#include <hip/hip_runtime.h>

// Problem constants: BOX=256, OS=1 -> S=256, NC=10, B=16, N=262144
#define S_    256
#define NC_   10
#define CHUNK 4096

typedef unsigned int u32;

__device__ __forceinline__ u32 f2bf(float f) {          // f32 -> bf16 (RNE)
    u32 u = __float_as_uint(f);
    return (u + 0x7fffu + ((u >> 16) & 1u)) >> 16;
}
__device__ __forceinline__ float bf2f(u32 h) { return __uint_as_float(h << 16); }

// Record: 24 B = 6 u32 (stored as 3 uint2):
//   w0 = qx | qy<<16   (tile-local coords, fixed-point 1/2048 px)
//   w1..w5 = 10 bf16 values packed in pairs
// cell-in-tile = (qy>>11)*32 + (qx>>11); rx = (qx&2047)/2048, ry likewise.

// ---- K1: per-chunk histogram over the 64 (8x8) 32px tiles ----
__global__ void __launch_bounds__(256)
k_hist(const float* __restrict__ points, u32* __restrict__ hist, int N) {
    __shared__ u32 h[64];
    if (threadIdx.x < 64) h[threadIdx.x] = 0;
    __syncthreads();
    const int cpb = N / CHUNK;
    const int b  = blockIdx.x / cpb;
    const int n0 = (blockIdx.x % cpb) * CHUNK;
    const float* pb = points + (size_t)b * 2 * N;
    for (int i = threadIdx.x; i < CHUNK; i += 256) {
        int n = n0 + i;
        float px = (pb[n] + 0.5f) * (float)S_;
        float py = (pb[(size_t)N + n] + 0.5f) * (float)S_;
        int xi = (int)floorf(px), yi = (int)floorf(py);
        int bin = ((yi >> 5) << 3) + (xi >> 5);
        atomicAdd(&h[bin], 1u);
    }
    __syncthreads();
    if (threadIdx.x < 64) hist[(size_t)blockIdx.x * 64 + threadIdx.x] = h[threadIdx.x];
}

// ---- K2: scan -> per-bin base/count + per-chunk cursors ----
__global__ void __launch_bounds__(1024)
k_scan(const u32* __restrict__ hist, u32* __restrict__ blockStart,
       u32* __restrict__ binBase, u32* __restrict__ binCnt,
       int cpb, int totalBins) {
    __shared__ u32 s[1024];
    const int g = threadIdx.x;
    const int batch = g >> 6, t = g & 63;
    u32 tot = 0;
    if (g < totalBins)
        for (int i = 0; i < cpb; ++i) tot += hist[(size_t)(batch * cpb + i) * 64 + t];
    s[g] = tot;
    __syncthreads();
    for (int off = 1; off < 1024; off <<= 1) {
        u32 y = (g >= off) ? s[g - off] : 0;
        __syncthreads();
        s[g] += y;
        __syncthreads();
    }
    if (g < totalBins) {
        u32 base = s[g] - tot;
        binBase[g] = base;
        binCnt[g]  = tot;
        u32 run = base;
        for (int i = 0; i < cpb; ++i) {
            size_t idx = (size_t)(batch * cpb + i) * 64 + t;
            u32 hv = hist[idx];
            blockStart[idx] = run;
            run += hv;
        }
    }
}

// ---- K3: scatter 24B records into tile-sorted order ----
__global__ void __launch_bounds__(256)
k_scatter(const float* __restrict__ points, const float* __restrict__ values,
          const u32* __restrict__ blockStart, uint2* __restrict__ recs, int N) {
    __shared__ u32 cur[64];
    if (threadIdx.x < 64) cur[threadIdx.x] = blockStart[(size_t)blockIdx.x * 64 + threadIdx.x];
    __syncthreads();
    const int cpb = N / CHUNK;
    const int b  = blockIdx.x / cpb;
    const int n0 = (blockIdx.x % cpb) * CHUNK;
    const float* pb = points + (size_t)b * 2 * N;
    const float* vb = values + (size_t)b * NC_ * N;
    for (int i = threadIdx.x; i < CHUNK; i += 256) {
        int n = n0 + i;
        float px = (pb[n] + 0.5f) * (float)S_;
        float py = (pb[(size_t)N + n] + 0.5f) * (float)S_;
        int xi = (int)floorf(px), yi = (int)floorf(py);
        int bin = ((yi >> 5) << 3) + (xi >> 5);
        u32 qx = __float2uint_rn((px - (float)(xi & ~31)) * 2048.0f);
        u32 qy = __float2uint_rn((py - (float)(yi & ~31)) * 2048.0f);
        qx = min(qx, 65535u); qy = min(qy, 65535u);
        u32 slot = atomicAdd(&cur[bin], 1u);
        float v[NC_];
#pragma unroll
        for (int c = 0; c < NC_; ++c) v[c] = vb[(size_t)c * N + n];
        size_t s3 = (size_t)slot * 3;
        recs[s3]     = make_uint2(qx | (qy << 16),        f2bf(v[0]) | (f2bf(v[1]) << 16));
        recs[s3 + 1] = make_uint2(f2bf(v[2]) | (f2bf(v[3]) << 16),
                                  f2bf(v[4]) | (f2bf(v[5]) << 16));
        recs[s3 + 2] = make_uint2(f2bf(v[6]) | (f2bf(v[7]) << 16),
                                  f2bf(v[8]) | (f2bf(v[9]) << 16));
    }
}

// ---- K4: per-tile counting sort to cell granularity ----
// One block per bin: LDS histogram over 1024 cells, scan, scatter to recsB,
// emit global cellStart/cellCnt. Only 2 LDS atomics per point.
__global__ void __launch_bounds__(256)
k_cellsort(const uint2* __restrict__ recsA, const u32* __restrict__ binBase,
           const u32* __restrict__ binCnt, uint2* __restrict__ recsB,
           u32* __restrict__ cellStart, u32* __restrict__ cellCnt) {
    __shared__ u32 cnt[1024];
    __shared__ u32 excl[1024];
    __shared__ u32 partial[256];
    const int tid = threadIdx.x;
    const int g = blockIdx.x;
    const int batch = g >> 6, t = g & 63;
    const int ox = (t & 7) * 32, oy = (t >> 3) * 32;
    const u32 base = binBase[g], n = binCnt[g];

#pragma unroll
    for (int k = 0; k < 4; ++k) cnt[tid + 256 * k] = 0;
    __syncthreads();

    // pass 1: histogram cells
    for (u32 i = tid; i < n; i += 256) {
        u32 w0 = recsA[(size_t)(base + i) * 3].x;
        u32 cell = ((w0 >> 27) << 5) | ((w0 >> 11) & 31);   // (qy>>11)*32 + (qx>>11)
        atomicAdd(&cnt[cell], 1u);
    }
    __syncthreads();

    // exclusive scan of 1024 counts (4 per thread + block scan of partials)
    u32 c0 = cnt[4 * tid], c1 = cnt[4 * tid + 1], c2 = cnt[4 * tid + 2], c3 = cnt[4 * tid + 3];
    u32 mysum = c0 + c1 + c2 + c3;
    partial[tid] = mysum;
    __syncthreads();
    for (int off = 1; off < 256; off <<= 1) {
        u32 v = (tid >= off) ? partial[tid - off] : 0;
        __syncthreads();
        partial[tid] += v;
        __syncthreads();
    }
    u32 pex = partial[tid] - mysum;
    excl[4 * tid]     = pex;
    excl[4 * tid + 1] = pex + c0;
    excl[4 * tid + 2] = pex + c0 + c1;
    excl[4 * tid + 3] = pex + c0 + c1 + c2;
    __syncthreads();

    // emit global cell offsets + reset cursors
#pragma unroll
    for (int k = 0; k < 4; ++k) {
        int cell = 4 * tid + k;
        int gx = ox + (cell & 31), gy = oy + (cell >> 5);
        size_t gc = ((size_t)batch << 16) + (gy << 8) + gx;
        cellStart[gc] = base + excl[cell];
        cellCnt[gc]   = cnt[cell];
    }
    __syncthreads();
#pragma unroll
    for (int k = 0; k < 4; ++k) cnt[tid + 256 * k] = excl[tid + 256 * k];
    __syncthreads();

    // pass 2: scatter records into cell order
    for (u32 i = tid; i < n; i += 256) {
        size_t sa = (size_t)(base + i) * 3;
        uint2 r0 = recsA[sa], r1 = recsA[sa + 1], r2 = recsA[sa + 2];
        u32 cell = ((r0.x >> 27) << 5) | ((r0.x >> 11) & 31);
        u32 slot = base + atomicAdd(&cnt[cell], 1u);
        size_t sb = (size_t)slot * 3;
        recsB[sb] = r0; recsB[sb + 1] = r1; recsB[sb + 2] = r2;
    }
}

// ---- K5: gather — one thread per pixel, all 10 channels in registers ----
__global__ void __launch_bounds__(256)
k_gather(const uint2* __restrict__ recs, const u32* __restrict__ cellStart,
         const u32* __restrict__ cellCnt, float* __restrict__ out) {
    const int t = threadIdx.x;
    const int x = blockIdx.x * 16 + (t & 15);
    const int y = blockIdx.y * 16 + (t >> 4);
    const int b = blockIdx.z;

    float acc[NC_];
#pragma unroll
    for (int c = 0; c < NC_; ++c) acc[c] = 0.0f;

    const size_t cbase = (size_t)b << 16;
#pragma unroll
    for (int dcy = -1; dcy <= 0; ++dcy) {
        int cy = y + dcy;
        if ((unsigned)cy >= S_) continue;
#pragma unroll
        for (int dcx = -1; dcx <= 0; ++dcx) {
            int cx = x + dcx;
            if ((unsigned)cx >= S_) continue;
            size_t gc = cbase + (cy << 8) + cx;
            u32 s = cellStart[gc], n = cellCnt[gc];
            for (u32 j = 0; j < n; ++j) {
                size_t sr = (size_t)(s + j) * 3;
                uint2 r0 = recs[sr], r1 = recs[sr + 1], r2 = recs[sr + 2];
                float rx = (float)(r0.x & 2047u)          * (1.0f / 2048.0f);
                float ry = (float)((r0.x >> 16) & 2047u)  * (1.0f / 2048.0f);
                float wx = (dcx == 0) ? (1.0f - rx) : rx;
                float wy = (dcy == 0) ? (1.0f - ry) : ry;
                float w = wx * wy;
                acc[0] += w * bf2f(r0.y & 0xffffu);
                acc[1] += w * bf2f(r0.y >> 16);
                acc[2] += w * bf2f(r1.x & 0xffffu);
                acc[3] += w * bf2f(r1.x >> 16);
                acc[4] += w * bf2f(r1.y & 0xffffu);
                acc[5] += w * bf2f(r1.y >> 16);
                acc[6] += w * bf2f(r2.x & 0xffffu);
                acc[7] += w * bf2f(r2.x >> 16);
                acc[8] += w * bf2f(r2.y & 0xffffu);
                acc[9] += w * bf2f(r2.y >> 16);
            }
        }
    }

    float* ob = out + (size_t)b * NC_ * S_ * S_ + y * S_ + x;
#pragma unroll
    for (int c = 0; c < NC_; ++c) ob[(size_t)c * S_ * S_] = acc[c];
}

// ---- fallback tier 2: round-2 deposit, ported to 24B records ----
__global__ void __launch_bounds__(256)
k_deposit(const uint2* __restrict__ recs, const u32* __restrict__ binBase,
          const u32* __restrict__ binCnt, float* __restrict__ out) {
    __shared__ float tile[NC_ * 33 * 33];
    for (int i = threadIdx.x; i < NC_ * 1089; i += 256) tile[i] = 0.0f;
    __syncthreads();
    const int g = blockIdx.x;
    const int batch = g >> 6, t = g & 63;
    const int ox = (t & 7) * 32, oy = (t >> 3) * 32;
    const u32 base = binBase[g], cnt = binCnt[g];
    for (u32 i = threadIdx.x; i < cnt; i += 256) {
        size_t sr = (size_t)(base + i) * 3;
        uint2 r0 = recs[sr], r1 = recs[sr + 1], r2 = recs[sr + 2];
        int lx = (r0.x >> 11) & 31, ly = r0.x >> 27;
        float rx = (float)(r0.x & 2047u)         * (1.0f / 2048.0f);
        float ry = (float)((r0.x >> 16) & 2047u) * (1.0f / 2048.0f);
        float w00 = (1.0f - rx) * (1.0f - ry);
        float w10 = rx * (1.0f - ry);
        float w01 = (1.0f - rx) * ry;
        float w11 = rx * ry;
        float v[NC_];
        v[0] = bf2f(r0.y & 0xffffu); v[1] = bf2f(r0.y >> 16);
        v[2] = bf2f(r1.x & 0xffffu); v[3] = bf2f(r1.x >> 16);
        v[4] = bf2f(r1.y & 0xffffu); v[5] = bf2f(r1.y >> 16);
        v[6] = bf2f(r2.x & 0xffffu); v[7] = bf2f(r2.x >> 16);
        v[8] = bf2f(r2.y & 0xffffu); v[9] = bf2f(r2.y >> 16);
        int i00 = ly * 33 + lx;
#pragma unroll
        for (int c = 0; c < NC_; ++c) {
            float* tc = tile + c * 1089 + i00;
            atomicAdd(tc,      w00 * v[c]);
            atomicAdd(tc + 1,  w10 * v[c]);
            atomicAdd(tc + 33, w01 * v[c]);
            atomicAdd(tc + 34, w11 * v[c]);
        }
    }
    __syncthreads();
    float* ob = out + (size_t)batch * NC_ * S_ * S_;
    for (int i = threadIdx.x; i < NC_ * 1089; i += 256) {
        int c = i / 1089, cell = i % 1089;
        int ly = cell / 33, lx = cell % 33;
        int gx = ox + lx, gy = oy + ly;
        if (gx >= S_ || gy >= S_) continue;
        float val = tile[i];
        float* dst = ob + (size_t)c * S_ * S_ + gy * S_ + gx;
        bool border = (lx == 0) | (lx == 32) | (ly == 0) | (ly == 32);
        if (border) atomicAdd(dst, val);
        else        *dst = val;
    }
}

// ---- fallback tier 3: direct atomic scatter ----
__global__ void __launch_bounds__(256)
scatter_cic_kernel(const float* __restrict__ points,
                   const float* __restrict__ values,
                   float* __restrict__ out, int N) {
    const int n = blockIdx.x * blockDim.x + threadIdx.x;
    const int b = blockIdx.y;
    if (n >= N) return;
    const float* pb = points + (size_t)b * 2 * N;
    const float px = (pb[n] + 0.5f) * (float)S_;
    const float py = (pb[(size_t)N + n] + 0.5f) * (float)S_;
    const float xf = floorf(px), yf = floorf(py);
    const float rx = px - xf, ry = py - yf;
    const int xi = (int)xf, yi = (int)yf;
    const float* vb = values + (size_t)b * NC_ * N + n;
    float v[NC_];
#pragma unroll
    for (int c = 0; c < NC_; ++c) v[c] = vb[(size_t)c * N];
    float* ob = out + (size_t)b * NC_ * S_ * S_;
#pragma unroll
    for (int dx = 0; dx < 2; ++dx) {
        const int x_ = xi + dx;
        if (x_ < 0 || x_ >= S_) continue;
        const float wx = dx ? rx : (1.0f - rx);
#pragma unroll
        for (int dy = 0; dy < 2; ++dy) {
            const int y_ = yi + dy;
            if (y_ < 0 || y_ >= S_) continue;
            const float w = wx * (dy ? ry : (1.0f - ry));
            const int idx = y_ * S_ + x_;
#pragma unroll
            for (int c = 0; c < NC_; ++c)
                atomicAdd(ob + (size_t)c * S_ * S_ + idx, w * v[c]);
        }
    }
}

extern "C" void kernel_launch(void* const* d_in, const int* in_sizes, int n_in,
                              void* d_out, int out_size, void* d_ws, size_t ws_size,
                              hipStream_t stream) {
    const float* points = (const float*)d_in[0];   // [B, 2, N]
    const float* values = (const float*)d_in[1];   // [B, NC, N]
    float* out = (float*)d_out;                    // [B, NC, S, S]

    const int B = out_size / (NC_ * S_ * S_);      // 16
    const int N = in_sizes[0] / (2 * B);           // 262144

    const size_t P = (size_t)B * N;
    const int cpb = N / CHUNK;
    const int chunksTotal = B * cpb;               // 1024
    const int totalBins = B * 64;                  // 1024

    const size_t recBytes   = P * 24;              // 100.7 MB per record array
    const size_t histElems  = (size_t)chunksTotal * 64;
    const size_t cellElems  = (size_t)B * 65536;
    const size_t auxBytes   = 2 * histElems * 4 + 2 * (size_t)totalBins * 4 + 256;
    const size_t wsPrimary  = 2 * recBytes + auxBytes + 2 * cellElems * 4;
    const size_t wsTier2    = recBytes + auxBytes;

    const bool shapeOk = (N % CHUNK == 0) && (B == 16);

    if (shapeOk && ws_size >= wsPrimary) {
        char* w = (char*)d_ws;
        uint2* recsA    = (uint2*)w;
        uint2* recsB    = (uint2*)(w + recBytes);
        u32* hist       = (u32*)(w + 2 * recBytes);
        u32* blockStart = hist + histElems;
        u32* binBase    = blockStart + histElems;
        u32* binCnt     = binBase + totalBins;
        u32* cellStart  = binCnt + totalBins;
        u32* cellCnt    = cellStart + cellElems;

        k_hist<<<chunksTotal, 256, 0, stream>>>(points, hist, N);
        k_scan<<<1, 1024, 0, stream>>>(hist, blockStart, binBase, binCnt, cpb, totalBins);
        k_scatter<<<chunksTotal, 256, 0, stream>>>(points, values, blockStart, recsA, N);
        k_cellsort<<<totalBins, 256, 0, stream>>>(recsA, binBase, binCnt, recsB, cellStart, cellCnt);
        dim3 ggrid(S_ / 16, S_ / 16, B);
        k_gather<<<ggrid, 256, 0, stream>>>(recsB, cellStart, cellCnt, out);
        // every output element is written by k_gather -> no memset needed
    } else if (shapeOk && ws_size >= wsTier2) {
        hipMemsetAsync(d_out, 0, (size_t)out_size * sizeof(float), stream);
        char* w = (char*)d_ws;
        uint2* recsA    = (uint2*)w;
        u32* hist       = (u32*)(w + recBytes);
        u32* blockStart = hist + histElems;
        u32* binBase    = blockStart + histElems;
        u32* binCnt     = binBase + totalBins;
        k_hist<<<chunksTotal, 256, 0, stream>>>(points, hist, N);
        k_scan<<<1, 1024, 0, stream>>>(hist, blockStart, binBase, binCnt, cpb, totalBins);
        k_scatter<<<chunksTotal, 256, 0, stream>>>(points, values, blockStart, recsA, N);
        k_deposit<<<totalBins, 256, 0, stream>>>(recsA, binBase, binCnt, out);
    } else {
        hipMemsetAsync(d_out, 0, (size_t)out_size * sizeof(float), stream);
        dim3 block(256, 1, 1);
        dim3 grid((N + 255) / 256, B, 1);
        scatter_cic_kernel<<<grid, block, 0, stream>>>(points, values, out, N);
    }
}

// Round 4
// 464.543 us; speedup vs baseline: 17.3793x; 1.1771x over previous
//
#include <hip/hip_runtime.h>

// Problem constants: BOX=256, OS=1 -> S=256, NC=10, B=16, N=262144
#define S_     256
#define NC_    10
#define CHUNK  4096
#define NBIN   256          // 16x16 tiles of 16x16 px per batch
#define CAP    1536         // max records staged in LDS per tile (~16 sigma)
#define RSTR   7            // LDS record stride in u32 (padded: breaks bank conflicts)

typedef unsigned int u32;

__device__ __forceinline__ u32 f2bf(float f) {          // f32 -> bf16 (RNE)
    u32 u = __float_as_uint(f);
    return (u + 0x7fffu + ((u >> 16) & 1u)) >> 16;
}
__device__ __forceinline__ float bf2f(u32 h) { return __uint_as_float(h << 16); }

// Record (24 B, 3x uint2): w0 = qx | qy<<16 (tile-local coords, fp 1/2048 px,
// qx in [0,32767]); w1..w5 = 10 bf16 values. cell-in-tile = (qy>>11)*16+(qx>>11).

// ---- K1: per-chunk histogram over the 256 16px-tiles of its batch ----
__global__ void __launch_bounds__(256)
k_hist(const float* __restrict__ points, u32* __restrict__ hist, int N) {
    __shared__ u32 h[NBIN];
    h[threadIdx.x] = 0;
    __syncthreads();
    const int cpb = N / CHUNK;
    const int b  = blockIdx.x / cpb;
    const int n0 = (blockIdx.x % cpb) * CHUNK;
    const float* pb = points + (size_t)b * 2 * N;
    for (int i = threadIdx.x; i < CHUNK; i += 256) {
        int n = n0 + i;
        float px = (pb[n] + 0.5f) * (float)S_;
        float py = (pb[(size_t)N + n] + 0.5f) * (float)S_;
        int xi = (int)floorf(px), yi = (int)floorf(py);
        int bin = ((yi >> 4) << 4) + (xi >> 4);
        atomicAdd(&h[bin], 1u);
    }
    __syncthreads();
    hist[(size_t)blockIdx.x * NBIN + threadIdx.x] = h[threadIdx.x];
}

// ---- K2: one block per batch; scan 256 bins, emit bases + per-chunk cursors ----
__global__ void __launch_bounds__(256)
k_scan(const u32* __restrict__ hist, u32* __restrict__ blockStart,
       u32* __restrict__ binBase, u32* __restrict__ binCnt, int cpb, int N) {
    __shared__ u32 s[256];
    const int b = blockIdx.x, t = threadIdx.x;
    u32 tot = 0;
    for (int i = 0; i < cpb; ++i) tot += hist[(size_t)(b * cpb + i) * NBIN + t];
    s[t] = tot;
    __syncthreads();
    for (int off = 1; off < 256; off <<= 1) {
        u32 y = (t >= off) ? s[t - off] : 0;
        __syncthreads();
        s[t] += y;
        __syncthreads();
    }
    u32 base = (u32)b * (u32)N + s[t] - tot;             // batch-major layout
    binBase[b * NBIN + t] = base;
    binCnt[b * NBIN + t]  = tot;
    u32 run = base;
    for (int i = 0; i < cpb; ++i) {
        size_t idx = (size_t)(b * cpb + i) * NBIN + t;
        u32 hv = hist[idx];
        blockStart[idx] = run;
        run += hv;
    }
}

// ---- K3: scatter 24B records into tile-sorted order ----
__global__ void __launch_bounds__(256)
k_scatter(const float* __restrict__ points, const float* __restrict__ values,
          const u32* __restrict__ blockStart, uint2* __restrict__ recs, int N) {
    __shared__ u32 cur[NBIN];
    cur[threadIdx.x] = blockStart[(size_t)blockIdx.x * NBIN + threadIdx.x];
    __syncthreads();
    const int cpb = N / CHUNK;
    const int b  = blockIdx.x / cpb;
    const int n0 = (blockIdx.x % cpb) * CHUNK;
    const float* pb = points + (size_t)b * 2 * N;
    const float* vb = values + (size_t)b * NC_ * N;
    for (int i = threadIdx.x; i < CHUNK; i += 256) {
        int n = n0 + i;
        float px = (pb[n] + 0.5f) * (float)S_;
        float py = (pb[(size_t)N + n] + 0.5f) * (float)S_;
        int xi = (int)floorf(px), yi = (int)floorf(py);
        int bin = ((yi >> 4) << 4) + (xi >> 4);
        u32 qx = __float2uint_rn((px - (float)(xi & ~15)) * 2048.0f);
        u32 qy = __float2uint_rn((py - (float)(yi & ~15)) * 2048.0f);
        qx = min(qx, 32767u); qy = min(qy, 32767u);
        u32 slot = atomicAdd(&cur[bin], 1u);
        float v[NC_];
#pragma unroll
        for (int c = 0; c < NC_; ++c) v[c] = vb[(size_t)c * N + n];
        size_t s3 = (size_t)slot * 3;
        recs[s3]     = make_uint2(qx | (qy << 16),        f2bf(v[0]) | (f2bf(v[1]) << 16));
        recs[s3 + 1] = make_uint2(f2bf(v[2]) | (f2bf(v[3]) << 16),
                                  f2bf(v[4]) | (f2bf(v[5]) << 16));
        recs[s3 + 2] = make_uint2(f2bf(v[6]) | (f2bf(v[7]) << 16),
                                  f2bf(v[8]) | (f2bf(v[9]) << 16));
    }
}

// ---- K4 fused: in-LDS cell sort + register gather, one block per tile ----
// Writes 15x15 interior pixels (full sums) with plain stores; 17x17 border
// partials go to borderBuf for k_border to combine. No global atomics.
__global__ void __launch_bounds__(256)
k_fused(const uint2* __restrict__ recs, const u32* __restrict__ binBase,
        const u32* __restrict__ binCnt, float* __restrict__ out,
        float* __restrict__ borderBuf) {
    __shared__ u32 cnt[NBIN];          // histogram -> cursor -> cell end
    __shared__ u32 excl[NBIN];         // cell start
    __shared__ u32 sc[NBIN];           // scan scratch
    __shared__ u32 lrec[CAP * RSTR];   // 43 KB cell-sorted records

    const int tid = threadIdx.x;
    const int g = blockIdx.x;                       // batch*256 + tile
    const int batch = g >> 8, t = g & 255;
    const int ox = (t & 15) * 16, oy = (t >> 4) * 16;
    const u32 base = binBase[g];
    const u32 n = min(binCnt[g], (u32)CAP);         // overflow -> k_cleanup

    cnt[tid] = 0;
    __syncthreads();

    // phase a: stage segment into registers + cell histogram
    u32 r[6][6];
    int cell[6];
#pragma unroll
    for (int k = 0; k < 6; ++k) {
        int i = k * 256 + tid;
        cell[k] = -1;
        if (i < (int)n) {
            size_t sa = (size_t)(base + i) * 3;
            uint2 a = recs[sa], b2 = recs[sa + 1], c2 = recs[sa + 2];
            r[k][0] = a.x;  r[k][1] = a.y;
            r[k][2] = b2.x; r[k][3] = b2.y;
            r[k][4] = c2.x; r[k][5] = c2.y;
            u32 qx = a.x & 0xffffu, qy = a.x >> 16;
            cell[k] = (int)(((qy >> 11) << 4) | (qx >> 11));
            atomicAdd(&cnt[cell[k]], 1u);
        }
    }
    __syncthreads();

    // phase b: exclusive scan of 256 cell counts
    u32 c = cnt[tid];
    sc[tid] = c;
    __syncthreads();
    for (int off = 1; off < 256; off <<= 1) {
        u32 y = (tid >= off) ? sc[tid - off] : 0;
        __syncthreads();
        sc[tid] += y;
        __syncthreads();
    }
    excl[tid] = sc[tid] - c;
    __syncthreads();
    cnt[tid] = excl[tid];                            // cursor
    __syncthreads();

    // phase c: scatter registers into LDS in cell order
#pragma unroll
    for (int k = 0; k < 6; ++k) {
        if (cell[k] >= 0) {
            u32 o = atomicAdd(&cnt[cell[k]], 1u) * RSTR;
#pragma unroll
            for (int w = 0; w < 6; ++w) lrec[o + w] = r[k][w];
        }
    }
    __syncthreads();                                 // cnt[c] is now cell end

    // phase d: gather 17x17 pixel partials from LDS
    for (int p = tid; p < 289; p += 256) {
        int lx = p % 17, ly = p / 17;
        float acc[NC_];
#pragma unroll
        for (int q = 0; q < NC_; ++q) acc[q] = 0.0f;
#pragma unroll
        for (int dy = 0; dy < 2; ++dy) {
            int cy = ly - 1 + dy;                    // dy=1 -> own cell (w=1-ry)
            if ((unsigned)cy >= 16u) continue;
#pragma unroll
            for (int dx = 0; dx < 2; ++dx) {
                int cx = lx - 1 + dx;
                if ((unsigned)cx >= 16u) continue;
                int cc = (cy << 4) | cx;
                u32 j1 = cnt[cc];
                for (u32 j = excl[cc]; j < j1; ++j) {
                    u32 o = j * RSTR;
                    u32 w0 = lrec[o];
                    float rx = (float)(w0 & 2047u)         * (1.0f / 2048.0f);
                    float ry = (float)((w0 >> 16) & 2047u) * (1.0f / 2048.0f);
                    float w = (dx ? (1.0f - rx) : rx) * (dy ? (1.0f - ry) : ry);
                    u32 w1 = lrec[o + 1], w2 = lrec[o + 2], w3 = lrec[o + 3],
                        w4 = lrec[o + 4], w5 = lrec[o + 5];
                    acc[0] += w * bf2f(w1 & 0xffffu); acc[1] += w * bf2f(w1 >> 16);
                    acc[2] += w * bf2f(w2 & 0xffffu); acc[3] += w * bf2f(w2 >> 16);
                    acc[4] += w * bf2f(w3 & 0xffffu); acc[5] += w * bf2f(w3 >> 16);
                    acc[6] += w * bf2f(w4 & 0xffffu); acc[7] += w * bf2f(w4 >> 16);
                    acc[8] += w * bf2f(w5 & 0xffffu); acc[9] += w * bf2f(w5 >> 16);
                }
            }
        }
        bool interior = (lx >= 1) & (lx <= 15) & (ly >= 1) & (ly <= 15);
        if (interior) {
            int gx = ox + lx, gy = oy + ly;
            float* ob = out + (size_t)batch * NC_ * S_ * S_ + gy * S_ + gx;
#pragma unroll
            for (int q = 0; q < NC_; ++q) ob[(size_t)q * S_ * S_] = acc[q];
        } else {
            float* bb = borderBuf + ((size_t)g * 289 + p) * NC_;
#pragma unroll
            for (int q = 0; q < NC_; ++q) bb[q] = acc[q];
        }
    }
}

// ---- K5: combine border partials (<=2x2 tiles per border pixel) ----
__global__ void __launch_bounds__(256)
k_border(const float* __restrict__ borderBuf, float* __restrict__ out) {
    int idx = blockIdx.x * 256 + threadIdx.x;        // b*65536 + gy*256 + gx
    int b = idx >> 16, rem = idx & 65535;
    int gy = rem >> 8, gx = rem & 255;
    bool bx = (gx & 15) == 0, by = (gy & 15) == 0;
    if (!bx && !by) return;

    int txs[2], lxs[2], nx = 0;
    if (bx) {
        if (gx > 0) { txs[nx] = (gx >> 4) - 1; lxs[nx] = 16; ++nx; }
        txs[nx] = gx >> 4; lxs[nx] = 0; ++nx;
    } else { txs[0] = gx >> 4; lxs[0] = gx & 15; nx = 1; }
    int tys[2], lys[2], ny = 0;
    if (by) {
        if (gy > 0) { tys[ny] = (gy >> 4) - 1; lys[ny] = 16; ++ny; }
        tys[ny] = gy >> 4; lys[ny] = 0; ++ny;
    } else { tys[0] = gy >> 4; lys[0] = gy & 15; ny = 1; }

    float acc[NC_];
#pragma unroll
    for (int q = 0; q < NC_; ++q) acc[q] = 0.0f;
    for (int j = 0; j < ny; ++j)
        for (int i = 0; i < nx; ++i) {
            int g = (b << 8) + (tys[j] << 4) + txs[i];
            int p = lys[j] * 17 + lxs[i];
            const float* bb = borderBuf + ((size_t)g * 289 + p) * NC_;
#pragma unroll
            for (int q = 0; q < NC_; ++q) acc[q] += bb[q];
        }
    float* ob = out + (size_t)b * NC_ * S_ * S_ + gy * S_ + gx;
#pragma unroll
    for (int q = 0; q < NC_; ++q) ob[(size_t)q * S_ * S_] = acc[q];
}

// ---- K6: overflow cleanup (normally a no-op; strict correctness) ----
__global__ void __launch_bounds__(256)
k_cleanup(const uint2* __restrict__ recs, const u32* __restrict__ binBase,
          const u32* __restrict__ binCnt, float* __restrict__ out, int nTiles) {
    int g = blockIdx.x * 256 + threadIdx.x;
    if (g >= nTiles) return;
    u32 n = binCnt[g];
    if (n <= (u32)CAP) return;
    int batch = g >> 8, t = g & 255;
    int ox = (t & 15) * 16, oy = (t >> 4) * 16;
    u32 base = binBase[g];
    float* ob = out + (size_t)batch * NC_ * S_ * S_;
    for (u32 i = CAP; i < n; ++i) {
        size_t sa = (size_t)(base + i) * 3;
        uint2 a = recs[sa], b2 = recs[sa + 1], c2 = recs[sa + 2];
        u32 qx = a.x & 0xffffu, qy = a.x >> 16;
        int xi = ox + (int)(qx >> 11), yi = oy + (int)(qy >> 11);
        float rx = (float)(qx & 2047u) * (1.0f / 2048.0f);
        float ry = (float)(qy & 2047u) * (1.0f / 2048.0f);
        float v[NC_];
        v[0] = bf2f(a.y & 0xffffu);  v[1] = bf2f(a.y >> 16);
        v[2] = bf2f(b2.x & 0xffffu); v[3] = bf2f(b2.x >> 16);
        v[4] = bf2f(b2.y & 0xffffu); v[5] = bf2f(b2.y >> 16);
        v[6] = bf2f(c2.x & 0xffffu); v[7] = bf2f(c2.x >> 16);
        v[8] = bf2f(c2.y & 0xffffu); v[9] = bf2f(c2.y >> 16);
        for (int dx = 0; dx < 2; ++dx) {
            int x_ = xi + dx; if (x_ >= S_) continue;
            float wx = dx ? rx : (1.0f - rx);
            for (int dy = 0; dy < 2; ++dy) {
                int y_ = yi + dy; if (y_ >= S_) continue;
                float w = wx * (dy ? ry : (1.0f - ry));
                for (int c = 0; c < NC_; ++c)
                    atomicAdd(ob + (size_t)c * S_ * S_ + y_ * S_ + x_, w * v[c]);
            }
        }
    }
}

// ---- fallback: direct atomic scatter (any shape) ----
__global__ void __launch_bounds__(256)
scatter_cic_kernel(const float* __restrict__ points,
                   const float* __restrict__ values,
                   float* __restrict__ out, int N) {
    const int n = blockIdx.x * blockDim.x + threadIdx.x;
    const int b = blockIdx.y;
    if (n >= N) return;
    const float* pb = points + (size_t)b * 2 * N;
    const float px = (pb[n] + 0.5f) * (float)S_;
    const float py = (pb[(size_t)N + n] + 0.5f) * (float)S_;
    const float xf = floorf(px), yf = floorf(py);
    const float rx = px - xf, ry = py - yf;
    const int xi = (int)xf, yi = (int)yf;
    const float* vb = values + (size_t)b * NC_ * N + n;
    float v[NC_];
#pragma unroll
    for (int c = 0; c < NC_; ++c) v[c] = vb[(size_t)c * N];
    float* ob = out + (size_t)b * NC_ * S_ * S_;
#pragma unroll
    for (int dx = 0; dx < 2; ++dx) {
        const int x_ = xi + dx;
        if (x_ < 0 || x_ >= S_) continue;
        const float wx = dx ? rx : (1.0f - rx);
#pragma unroll
        for (int dy = 0; dy < 2; ++dy) {
            const int y_ = yi + dy;
            if (y_ < 0 || y_ >= S_) continue;
            const float w = wx * (dy ? ry : (1.0f - ry));
            const int idx = y_ * S_ + x_;
#pragma unroll
            for (int c = 0; c < NC_; ++c)
                atomicAdd(ob + (size_t)c * S_ * S_ + idx, w * v[c]);
        }
    }
}

extern "C" void kernel_launch(void* const* d_in, const int* in_sizes, int n_in,
                              void* d_out, int out_size, void* d_ws, size_t ws_size,
                              hipStream_t stream) {
    const float* points = (const float*)d_in[0];   // [B, 2, N]
    const float* values = (const float*)d_in[1];   // [B, NC, N]
    float* out = (float*)d_out;                    // [B, NC, S, S]

    const int B = out_size / (NC_ * S_ * S_);      // 16
    const int N = in_sizes[0] / (2 * B);           // 262144

    const size_t P = (size_t)B * N;
    const int cpb = N / CHUNK;                     // 64
    const int chunksTotal = B * cpb;               // 1024
    const int nTiles = B * NBIN;                   // 4096

    const size_t recBytes    = P * 24;             // 100.7 MB
    const size_t histElems   = (size_t)chunksTotal * NBIN;
    const size_t borderElems = (size_t)nTiles * 289 * NC_;
    const size_t wsNeeded    = recBytes + 2 * histElems * 4 +
                               2 * (size_t)nTiles * 4 + borderElems * 4 + 256;

    const bool fast = (N % CHUNK == 0) && (N >= CHUNK) && (B > 0) &&
                      (P < (1u << 31) / 2) && (ws_size >= wsNeeded);

    if (fast) {
        char* w = (char*)d_ws;
        uint2* recsA     = (uint2*)w;
        u32* hist        = (u32*)(w + recBytes);
        u32* blockStart  = hist + histElems;
        u32* binBase     = blockStart + histElems;
        u32* binCnt      = binBase + nTiles;
        float* borderBuf = (float*)(binCnt + nTiles);

        k_hist<<<chunksTotal, 256, 0, stream>>>(points, hist, N);
        k_scan<<<B, 256, 0, stream>>>(hist, blockStart, binBase, binCnt, cpb, N);
        k_scatter<<<chunksTotal, 256, 0, stream>>>(points, values, blockStart, recsA, N);
        k_fused<<<nTiles, 256, 0, stream>>>(recsA, binBase, binCnt, out, borderBuf);
        k_border<<<(B * 65536) / 256, 256, 0, stream>>>(borderBuf, out);
        k_cleanup<<<(nTiles + 255) / 256, 256, 0, stream>>>(recsA, binBase, binCnt, out, nTiles);
        // every output pixel is written by k_fused (interior) or k_border -> no memset
    } else {
        hipMemsetAsync(d_out, 0, (size_t)out_size * sizeof(float), stream);
        dim3 block(256, 1, 1);
        dim3 grid((N + 255) / 256, B, 1);
        scatter_cic_kernel<<<grid, block, 0, stream>>>(points, values, out, N);
    }
}